// Round 3
// baseline (131.609 us; speedup 1.0000x reference)
//
#include <hip/hip_runtime.h>
#include <math.h>

// Problem constants (match reference)
#define Lp 1024
#define Bp 64
#define Tt 128          // tile rows
#define NTILE 8         // Lp / Tt
#define NPAIR 36        // NTILE*(NTILE+1)/2 triangular tile pairs
#define BPB 2           // batches per block (shared staging)

typedef float v2 __attribute__((ext_vector_type(2)));
static __device__ __forceinline__ v2 splat2(float s) { v2 r; r.x = s; r.y = s; return r; }
static __device__ __forceinline__ v2 lo2(float4 v)   { v2 r; r.x = v.x; r.y = v.y; return r; }
static __device__ __forceinline__ v2 hi2(float4 v)   { v2 r; r.x = v.z; r.y = v.w; return r; }

// Identity: sum_{pairs} mi*mj*(dx-dy)^2
//         = sum mi*mj*(d2x+d2y)  -  2*sum mi*mj*dx*dy
// First term O(L) via moments; O(L^2) kernel only accumulates sqrt(d2x*d2y).
// Subtract-form d2 is exactly >= 0, so the product under sqrt is safe.
//
// Block = (2 batches, triangular tile-pair). 256 threads.
// Waves 0-1 compute batch b0, waves 2-3 batch b0+1 -> staging cost and
// block prologue/epilogue amortized over 2 batches; per-lane global loads
// are contiguous 24-B chunks (3x float2) instead of scattered 12 B.
__global__ __launch_bounds__(256, 4) void drmsd_main(
    const float* __restrict__ x, const float* __restrict__ y,
    float* __restrict__ partials, float* __restrict__ moments)
{
    __shared__ __align__(16) float xs[2][3][BPB][Tt];   // [tile][comp][batch][row]
    __shared__ __align__(16) float ys[2][3][BPB][Tt];
    __shared__ __align__(16) float msk[2][BPB][Tt];
    __shared__ float red[4];
    __shared__ float mred[4][9];

    const int b0 = blockIdx.x * BPB;   // first batch of this block
    const int p  = blockIdx.y;         // triangular pair index 0..35
    const int t  = threadIdx.x;

    // decode p -> (ti, tj), ti <= tj
    int ti = 0, base = 0;
    while (p >= base + (NTILE - ti)) { base += (NTILE - ti); ++ti; }
    const int tj = ti + (p - base);

    // ---- stage: threads 0-127 -> i-tile (slot 0), 128-255 -> j-tile (slot 1)
    {
        const int which = t >> 7;
        const int r     = t & (Tt - 1);
        const int tile  = which ? tj : ti;
        const int row   = tile * Tt + r;
        const float* px = x + (size_t)row * (Bp * 3) + (size_t)b0 * 3;
        const float* py = y + (size_t)row * (Bp * 3) + (size_t)b0 * 3;
        // 24 contiguous bytes per array: both batches' coords (8-aligned: b0 even)
        const float2 xa = *(const float2*)(px + 0);
        const float2 xb = *(const float2*)(px + 2);
        const float2 xc = *(const float2*)(px + 4);
        const float2 ya = *(const float2*)(py + 0);
        const float2 yb = *(const float2*)(py + 2);
        const float2 yc = *(const float2*)(py + 4);
        xs[which][0][0][r] = xa.x; xs[which][1][0][r] = xa.y; xs[which][2][0][r] = xb.x;
        xs[which][0][1][r] = xb.y; xs[which][1][1][r] = xc.x; xs[which][2][1][r] = xc.y;
        ys[which][0][0][r] = ya.x; ys[which][1][0][r] = ya.y; ys[which][2][0][r] = yb.x;
        ys[which][0][1][r] = yb.y; ys[which][1][1][r] = yc.x; ys[which][2][1][r] = yc.y;
        msk[which][0][r] = ((ya.x + ya.y + yb.x) != 0.0f) ? 1.0f : 0.0f;
        msk[which][1][r] = ((yb.y + yc.x + yc.y) != 0.0f) ? 1.0f : 0.0f;
    }
    __syncthreads();

    const int wv = t >> 6;                     // wave 0..3
    const int wb = wv >> 1;                    // batch select 0/1
    const int tp = (t & 63) | ((wv & 1) << 6); // 0..127 within the batch's wave-pair
    const int rg = tp >> 4;                    // 0..7 i-group
    const int jc = (tp & 15) << 2;             // first of 4 j columns

    float total = 0.0f;

#pragma unroll
    for (int jj = 0; jj < 2; ++jj) {
        const int j0 = jj * 64 + jc;
        // current j-strip only (28 VGPRs) -- stays under the 128-VGPR cliff
        const float4 jx0 = *(const float4*)&xs[1][0][wb][j0];
        const float4 jx1 = *(const float4*)&xs[1][1][wb][j0];
        const float4 jx2 = *(const float4*)&xs[1][2][wb][j0];
        const float4 jy0 = *(const float4*)&ys[1][0][wb][j0];
        const float4 jy1 = *(const float4*)&ys[1][1][wb][j0];
        const float4 jy2 = *(const float4*)&ys[1][2][wb][j0];
        const float4 jm4 = *(const float4*)&msk[1][wb][j0];
#pragma unroll
        for (int q = 0; q < 4; ++q) {
            const int i0 = q * 32 + rg * 4;
            const float4 ix0 = *(const float4*)&xs[0][0][wb][i0];
            const float4 ix1 = *(const float4*)&xs[0][1][wb][i0];
            const float4 ix2 = *(const float4*)&xs[0][2][wb][i0];
            const float4 iy0 = *(const float4*)&ys[0][0][wb][i0];
            const float4 iy1 = *(const float4*)&ys[0][1][wb][i0];
            const float4 iy2 = *(const float4*)&ys[0][2][wb][i0];
            const float4 im4 = *(const float4*)&msk[0][wb][i0];
            const float xix[4] = { ix0.x, ix0.y, ix0.z, ix0.w };
            const float xiy[4] = { ix1.x, ix1.y, ix1.z, ix1.w };
            const float xiz[4] = { ix2.x, ix2.y, ix2.z, ix2.w };
            const float yix[4] = { iy0.x, iy0.y, iy0.z, iy0.w };
            const float yiy[4] = { iy1.x, iy1.y, iy1.z, iy1.w };
            const float yiz[4] = { iy2.x, iy2.y, iy2.z, iy2.w };
            const float mir[4] = { im4.x, im4.y, im4.z, im4.w };

            v2 acc[4];
#pragma unroll
            for (int r = 0; r < 4; ++r) acc[r] = splat2(0.0f);

#pragma unroll
            for (int s = 0; s < 2; ++s) {
                const v2 xjx = s ? hi2(jx0) : lo2(jx0);
                const v2 xjy = s ? hi2(jx1) : lo2(jx1);
                const v2 xjz = s ? hi2(jx2) : lo2(jx2);
                const v2 yjx = s ? hi2(jy0) : lo2(jy0);
                const v2 yjy = s ? hi2(jy1) : lo2(jy1);
                const v2 yjz = s ? hi2(jy2) : lo2(jy2);
                const v2 mj  = s ? hi2(jm4) : lo2(jm4);
#pragma unroll
                for (int r = 0; r < 4; ++r) {
                    const v2 ax = splat2(xix[r]) - xjx;
                    const v2 ay = splat2(xiy[r]) - xjy;
                    const v2 az = splat2(xiz[r]) - xjz;
                    const v2 d2x = ax * ax + ay * ay + az * az;  // pk_fma
                    const v2 bx = splat2(yix[r]) - yjx;
                    const v2 by = splat2(yiy[r]) - yjy;
                    const v2 bz = splat2(yiz[r]) - yjz;
                    const v2 d2y = bx * bx + by * by + bz * bz;
                    const v2 pr = d2x * d2y;                     // >= 0 exactly
                    v2 sq;
                    sq.x = __builtin_amdgcn_sqrtf(pr.x);
                    sq.y = __builtin_amdgcn_sqrtf(pr.y);
                    acc[r] = mj * sq + acc[r];                   // col mask, pk_fma
                }
            }
#pragma unroll
            for (int r = 0; r < 4; ++r)
                total = fmaf(acc[r].x + acc[r].y, mir[r], total); // row mask
        }
    }

    // ---- per-wave reduction; waves 0-1 are batch b0, waves 2-3 are b0+1
#pragma unroll
    for (int off = 32; off > 0; off >>= 1)
        total += __shfl_down(total, off, 64);
    if ((t & 63) == 0) red[wv] = total;
    __syncthreads();
    if (t == 0) {
        float s0 = red[0] + red[1];
        float s1 = red[2] + red[3];
        if (ti != tj) { s0 *= 2.0f; s1 *= 2.0f; }  // off-diag counted both orders
        partials[(size_t)p * Bp + b0]     = s0;
        partials[(size_t)p * Bp + b0 + 1] = s1;
    }

    // ---- diagonal blocks also emit their stripe's moments (data is in LDS)
    if (ti == tj) {
        const int l    = t & 63;
        const int rrow = ((wv & 1) << 6) | l;   // waves 0/2: rows 0-63, 1/3: 64-127
        float v[9];
        {
            const float x0 = xs[0][0][wb][rrow], x1 = xs[0][1][wb][rrow], x2 = xs[0][2][wb][rrow];
            const float y0 = ys[0][0][wb][rrow], y1 = ys[0][1][wb][rrow], y2 = ys[0][2][wb][rrow];
            const float m  = msk[0][wb][rrow];
            v[0] = m * x0; v[1] = m * x1; v[2] = m * x2;
            v[3] = m * fmaf(x0, x0, fmaf(x1, x1, x2 * x2));
            v[4] = m * y0; v[5] = m * y1; v[6] = m * y2;
            v[7] = m * fmaf(y0, y0, fmaf(y1, y1, y2 * y2));
            v[8] = m;
        }
#pragma unroll
        for (int k = 0; k < 9; ++k) {
#pragma unroll
            for (int off = 32; off > 0; off >>= 1)
                v[k] += __shfl_down(v[k], off, 64);
        }
        if (l == 0) {
#pragma unroll
            for (int k = 0; k < 9; ++k) mred[wv][k] = v[k];
        }
        __syncthreads();
        if (t < 9)
            moments[(size_t)(ti * 9 + t) * Bp + b0] = mred[0][t] + mred[1][t];
        else if (t >= 64 && t < 73)
            moments[(size_t)(ti * 9 + (t - 64)) * Bp + b0 + 1] =
                mred[2][t - 64] + mred[3][t - 64];
    }
}

// Single wave: combine closed-form (d2x+d2y) term with cross-term partials.
__global__ __launch_bounds__(64) void drmsd_final(
    const float* __restrict__ partials, const float* __restrict__ moments,
    float* __restrict__ out)
{
    const int b = threadIdx.x;   // 0..63, one batch per lane
    double cross = 0.0;
#pragma unroll
    for (int pp = 0; pp < NPAIR; ++pp)
        cross += (double)partials[(size_t)pp * Bp + b];   // coalesced

    double mo[9];
#pragma unroll
    for (int k = 0; k < 9; ++k) mo[k] = 0.0;
#pragma unroll
    for (int s = 0; s < NTILE; ++s) {
#pragma unroll
        for (int k = 0; k < 9; ++k)
            mo[k] += (double)moments[(size_t)(s * 9 + k) * Bp + b];  // coalesced
    }
    const double sx0 = mo[0], sx1 = mo[1], sx2 = mo[2], qx = mo[3];
    const double sy0 = mo[4], sy1 = mo[5], sy2 = mo[6], qy = mo[7];
    const double M   = mo[8];
    const double term1 = 2.0 * M * (qx + qy)
        - 2.0 * (sx0*sx0 + sx1*sx1 + sx2*sx2 + sy0*sy0 + sy1*sy1 + sy2*sy2);

    double su = term1 - 2.0 * cross;
    su = su > 0.0 ? su : 0.0;        // guard rounding when x == y
    double pb = sqrt(su);
#pragma unroll
    for (int off = 32; off > 0; off >>= 1)
        pb += __shfl_down(pb, off, 64);
    if (b == 0) {
        const double denom = sqrt((double)Lp * (double)Lp / 2.0 - (double)Lp);
        out[0] = (float)(pb / denom / (double)Bp);
    }
}

extern "C" void kernel_launch(void* const* d_in, const int* in_sizes, int n_in,
                              void* d_out, int out_size, void* d_ws, size_t ws_size,
                              hipStream_t stream) {
    const float* x = (const float*)d_in[0];
    const float* y = (const float*)d_in[1];
    float* out      = (float*)d_out;
    float* partials = (float*)d_ws;                   // NPAIR*Bp floats
    float* moments  = partials + NPAIR * Bp;          // NTILE*9*Bp floats (< 24 KB)

    dim3 grid(Bp / BPB, NPAIR);
    drmsd_main<<<grid, 256, 0, stream>>>(x, y, partials, moments);
    drmsd_final<<<1, 64, 0, stream>>>(partials, moments, out);
}